// Round 7
// baseline (432.577 us; speedup 1.0000x reference)
//
#include <hip/hip_runtime.h>

typedef unsigned short u16;
typedef __bf16 bf16x8 __attribute__((ext_vector_type(8)));
typedef __bf16 bf16x2_t __attribute__((ext_vector_type(2)));
typedef float f32x4 __attribute__((ext_vector_type(4)));

#define AS1 __attribute__((address_space(1)))
#define AS3 __attribute__((address_space(3)))

__device__ __forceinline__ void gld16(const void* g, void* l) {
  // 16B per lane: global per-lane gather -> LDS (wave-uniform base + lane*16)
  __builtin_amdgcn_global_load_lds((const AS1 void*)g, (AS3 void*)l, 16, 0, 0);
}

__device__ __forceinline__ u16 f2bf(float f) {
  union { float f; unsigned int u; } v; v.f = f;
  unsigned int u = v.u;
  u += 0x7fffu + ((u >> 16) & 1u);
  return (u16)(u >> 16);
}
__device__ __forceinline__ float bf2f(u16 h) {
  union { unsigned int u; float f; } v; v.u = ((unsigned int)h) << 16; return v.f;
}
// pack 2 fp32 -> 2 bf16 in one HW instr where available
__device__ __forceinline__ unsigned int pk2(float a, float b) {
#if __has_builtin(__builtin_amdgcn_cvt_pk_bf16_f32)
  union { bf16x2_t v; unsigned int u; } c;
  c.v = __builtin_amdgcn_cvt_pk_bf16_f32(a, b);
  return c.u;
#else
  return (unsigned int)f2bf(a) | ((unsigned int)f2bf(b) << 16);
#endif
}
// fast GELU: v * sigmoid(v*(1.5957691 + 0.0713548*v^2)); raw v_rcp (1 instr)
__device__ __forceinline__ float gelu_f(float v) {
  float u = v * (1.5957691216f + 0.0713548163f * v * v);
  return v * __builtin_amdgcn_rcpf(1.0f + __expf(-u));
}

// ---------------- cast weights fp32 -> bf16 ----------------
// proj_w gets head-interleaved column permutation to match attn's packed stores:
// attn lane holds (d, d+16) pairs -> stored at cols (2d, 2d+1) within the head.
__global__ __launch_bounds__(256) void cast_weights(
    const float* __restrict__ w0, const float* __restrict__ w1,
    const float* __restrict__ w2, const float* __restrict__ w3,
    u16* __restrict__ o0, u16* __restrict__ o1,
    u16* __restrict__ o2, u16* __restrict__ o3) {
  int i = blockIdx.x * 256 + threadIdx.x;
  if (i < 110592) o0[i] = f2bf(w0[i]);   // qkv_w 576x192
  if (i < 36864) {                        // proj_w 192x192, k-permuted
    int n = i / 192, kp = i - n * 192;
    int h = kp >> 5, dp = kp & 31;
    int d = (dp & 1) ? ((dp >> 1) + 16) : (dp >> 1);
    o1[i] = f2bf(w1[n * 192 + h * 32 + d]);
  }
  if (i < 221184) o2[i] = f2bf(w2[i]);   // fc1_w 1152x192
  if (i < 221184) o3[i] = f2bf(w3[i]);   // fc2_w 192x1152
}

// ---------------- bias table [6][64(key m)][64(query r)]; key>=49 -> -1e30 ----
__global__ __launch_bounds__(256) void build_btab(
    const float* __restrict__ rpb, float* __restrict__ btab) {
  int id = blockIdx.x * 256 + threadIdx.x;   // 96*256 = 24576
  int head = id >> 12;
  int m = (id >> 6) & 63;
  int r = id & 63;
  float v;
  if (m >= 49) v = -1e30f;                   // key mask folds into bias
  else if (r >= 49) v = 0.0f;
  else {
    int mi = m / 7, mj = m - mi * 7;
    int ri = r / 7, rj = r - ri * 7;
    v = rpb[((ri - mi + 6) * 13 + (rj - mj + 6)) * 6 + head];
  }
  btab[id] = v;
}

// ---------------- layernorm (fp32 in, bf16 out), 1 wave per row of 192 ----------------
__global__ __launch_bounds__(256) void ln_kernel(
    const float* __restrict__ x, const float* __restrict__ g,
    const float* __restrict__ b, u16* __restrict__ out) {
  int row = blockIdx.x * 4 + (threadIdx.x >> 6);
  int lane = threadIdx.x & 63;
  const float* xr = x + (long)row * 192;
  float e0 = xr[lane], e1 = xr[lane + 64], e2 = xr[lane + 128];
  float s = e0 + e1 + e2;
  #pragma unroll
  for (int o = 1; o < 64; o <<= 1) s += __shfl_xor(s, o);
  float mean = s * (1.0f / 192.0f);
  float d0 = e0 - mean, d1 = e1 - mean, d2 = e2 - mean;
  float q = d0 * d0 + d1 * d1 + d2 * d2;
  #pragma unroll
  for (int o = 1; o < 64; o <<= 1) q += __shfl_xor(q, o);
  float rstd = rsqrtf(q * (1.0f / 192.0f) + 1e-5f);
  u16* orow = out + (long)row * 192;
  orow[lane]       = f2bf(d0 * rstd * g[lane]       + b[lane]);
  orow[lane + 64]  = f2bf(d1 * rstd * g[lane + 64]  + b[lane + 64]);
  orow[lane + 128] = f2bf(d2 * rstd * g[lane + 128] + b[lane + 128]);
}

// ---------------- MFMA GEMM: out[M,N] = A[M,K] @ W[N,K]^T + bias ----------------
// Round-4 proven kernel, verbatim. Block tile 128x192, 4 waves 2x2,
// double-buffered chunk=32, dynamic staging loop, generic 4-pass epilogue.
// MODE 0: store bf16. MODE 2: +resid(fp32) -> fp32.
template<int MODE>
__global__ __launch_bounds__(256, 3) void gemm_kernel(
    const u16* __restrict__ A, const u16* __restrict__ W,
    const float* __restrict__ bias, const float* __restrict__ resid,
    void* __restrict__ out, int N, int K) {
  constexpr int TT = 20;               // 8 A-tiles + 12 B-tiles per chunk
  constexpr int BUF = TT * 512;        // u16 per LDS buffer
  __shared__ u16 lds[2 * BUF];         // 40,960 B
  float* ct = (float*)lds;             // epilogue overlay: 64 x 100 fp32 (25,600 B)
  const int tid = threadIdx.x;
  const int wave = tid >> 6, lane = tid & 63;
  const int wm = wave >> 1, wn = wave & 1;
  const int quad = lane >> 4, l15 = lane & 15;
  const long bm = (long)blockIdx.x * 128;
  const int bn = blockIdx.y * 192;
  const int NC = K >> 5;

  // ---- prologue: stage chunk 0 into buf 0 (5 gld16 per wave) ----
  for (int t = wave; t < TT; t += 4) {
    const u16* g = (t < 8)
        ? (A + (bm + t * 16 + l15) * (long)K + quad * 8)
        : (W + (long)(bn + (t - 8) * 16 + l15) * K + quad * 8);
    gld16(g, &lds[t * 512]);
  }
  __syncthreads();

  f32x4 acc[4][6] = {};
  for (int c = 0; c < NC; c++) {
    const int cur = c & 1;
    if (c + 1 < NC) {
      const int kof = (c + 1) * 32 + quad * 8;
      u16* nb = &lds[(cur ^ 1) * BUF];
      for (int t = wave; t < TT; t += 4) {
        const u16* g = (t < 8)
            ? (A + (bm + t * 16 + l15) * (long)K + kof)
            : (W + (long)(bn + (t - 8) * 16 + l15) * K + kof);
        gld16(g, nb + t * 512);
      }
    }
    const u16* buf = lds + cur * BUF;
    bf16x8 af[4];
    #pragma unroll
    for (int mt = 0; mt < 4; mt++)
      af[mt] = *(const bf16x8*)&buf[(wm * 4 + mt) * 512 + lane * 8];
    #pragma unroll
    for (int nt = 0; nt < 6; nt++) {
      bf16x8 bfr = *(const bf16x8*)&buf[(8 + wn * 6 + nt) * 512 + lane * 8];
      #pragma unroll
      for (int mt = 0; mt < 4; mt++)
        acc[mt][nt] = __builtin_amdgcn_mfma_f32_16x16x32_bf16(af[mt], bfr, acc[mt][nt], 0, 0, 0);
    }
    __syncthreads();   // drains chunk c+1 staging; guards buf reuse
  }

  // ---- epilogue: 4 passes (2 row-halves h x 2 col-halves g) ----
  #pragma unroll
  for (int h = 0; h < 2; h++) {
    #pragma unroll
    for (int g = 0; g < 2; g++) {
      if (wm == h && wn == g) {
        #pragma unroll
        for (int nt = 0; nt < 6; nt++) {
          int col = nt * 16 + l15;
          float bi = bias[bn + g * 96 + col];
          #pragma unroll
          for (int mt = 0; mt < 4; mt++) {
            int row0 = mt * 16 + quad * 4;
            #pragma unroll
            for (int j = 0; j < 4; j++)
              ct[(row0 + j) * 100 + col] = acc[mt][nt][j] + bi;
          }
        }
      }
      __syncthreads();
      // 64 rows x 24 float4-groups = 1536 chunks, 6 per thread
      #pragma unroll
      for (int it = 0; it < 6; it++) {
        int cc = it * 256 + tid;
        int row = cc / 24, i = cc - row * 24;
        float4 v = *(const float4*)&ct[row * 100 + i * 4];
        long idx = (bm + h * 64 + row) * (long)N + bn + g * 96 + i * 4;
        if (MODE == 2) {
          const float4 rv = *(const float4*)(resid + idx);
          v.x += rv.x; v.y += rv.y; v.z += rv.z; v.w += rv.w;
          *(float4*)((float*)out + idx) = v;
        } else {
          uint2 pk;
          pk.x = pk2(v.x, v.y);
          pk.y = pk2(v.z, v.w);
          *(uint2*)((u16*)out + idx) = pk;
        }
      }
      if (!(h == 1 && g == 1)) __syncthreads();
    }
  }
}

// ---------------- FUSED MLP v2: out = resid + gelu(hA@W1^T + b1)@W2^T + b2 ----
// Round-6 lesson: weight-LDS staging cost 78 barrier intervals/block, each with
// a forced vmcnt(0) drain -> 148 us despite 6x fewer HBM bytes. v2: WEIGHTS
// NEVER TOUCH LDS. W1/W2 fragments are loaded straight from global into
// registers (884 KB shared by all 784 blocks -> L2-hot; wm-pair duplication
// absorbed by per-CU L1). Phase A is barrier-free: 36 dwordx4 loads + 72
// MFMAs per hc, freely software-pipelined by the compiler. Barriers: only
// 2/hc around the hid LDS handoff (12 total vs 78), with no VMEM to drain.
// Grid (784): 64-row block, 4 waves 2x2 (wave tile 32m x 96n).
//   phase A: acc1 = mfma(W1frag, hAfrag)  [swapped -> lane holds (n1, m)]
//   GELU -> hid LDS [m][n1] via uint2; barrier
//   phase B: acc2 += mfma(hidfrag, W2frag); barrier
// LDS 25,600 B (hid only). VGPR ~190 (haf 48 + acc1 48 + acc2 48 + wf).
__global__ __launch_bounds__(256, 2) void mlp_kernel(
    const u16* __restrict__ hA, const u16* __restrict__ W1,
    const float* __restrict__ b1, const u16* __restrict__ W2,
    const float* __restrict__ b2, const float* __restrict__ resid,
    float* __restrict__ out) {
  __shared__ u16 hid[64 * 200];    // 25,600 B
  float* ct = (float*)hid;         // epilogue overlay: 64 x 100 fp32
  const int tid = threadIdx.x;
  const int wave = tid >> 6, lane = tid & 63;
  const int wm = wave >> 1, wn = wave & 1;
  const int quad = lane >> 4, l15 = lane & 15;
  const long bm = (long)blockIdx.x * 64;

  // hA fragments resident in registers (rows bm + wm*32 + mt*16 + l15)
  bf16x8 haf[2][6];
  #pragma unroll
  for (int mt = 0; mt < 2; mt++)
    #pragma unroll
    for (int kc = 0; kc < 6; kc++)
      haf[mt][kc] = *(const bf16x8*)&hA[(bm + wm * 32 + mt * 16 + l15) * 192 + kc * 32 + quad * 8];

  // per-lane weight fragment base pointers
  // phase A frag (nt,kc,hc): W1[(hc*192 + wn*96 + nt*16 + l15)*192 + kc*32 + quad*8]
  // phase B frag (nt,kc,hc): W2[(wn*96 + nt*16 + l15)*1152 + hc*192 + kc*32 + quad*8]
  const u16* pw1 = W1 + (long)(wn * 96 + l15) * 192 + quad * 8;
  const u16* pw2 = W2 + (long)(wn * 96 + l15) * 1152 + quad * 8;

  f32x4 acc2[2][6] = {};
  for (int hc = 0; hc < 6; ++hc) {
    // ---- phase A: hid_c = hA @ W1[hc]^T + b1 (swapped operands, no LDS) ----
    f32x4 acc1[6][2];
    #pragma unroll
    for (int nt = 0; nt < 6; nt++) {
      f32x4 bv = *(const f32x4*)&b1[hc * 192 + wn * 96 + nt * 16 + quad * 4];
      acc1[nt][0] = bv;
      acc1[nt][1] = bv;
    }
    const u16* w1h = pw1 + (long)hc * 36864;   // hc*192*192
    #pragma unroll
    for (int kc = 0; kc < 6; kc++) {
      #pragma unroll
      for (int nt = 0; nt < 6; nt++) {
        bf16x8 wf = *(const bf16x8*)(w1h + nt * 3072 + kc * 32);   // nt*16*192
        acc1[nt][0] = __builtin_amdgcn_mfma_f32_16x16x32_bf16(wf, haf[0][kc], acc1[nt][0], 0, 0, 0);
        acc1[nt][1] = __builtin_amdgcn_mfma_f32_16x16x32_bf16(wf, haf[1][kc], acc1[nt][1], 0, 0, 0);
      }
    }
    // ---- GELU -> hid LDS: lane holds (n1 = wn*96+nt*16+quad*4+j, m = wm*32+mt*16+l15) ----
    #pragma unroll
    for (int nt = 0; nt < 6; nt++)
      #pragma unroll
      for (int mt = 0; mt < 2; mt++) {
        uint2 pk;
        pk.x = pk2(gelu_f(acc1[nt][mt][0]), gelu_f(acc1[nt][mt][1]));
        pk.y = pk2(gelu_f(acc1[nt][mt][2]), gelu_f(acc1[nt][mt][3]));
        *(uint2*)&hid[(wm * 32 + mt * 16 + l15) * 200 + wn * 96 + nt * 16 + quad * 4] = pk;
      }
    __syncthreads();   // all GELU writes visible before phase B reads
    // ---- phase B: acc2 += hid_c @ W2[:, hc-chunk]^T (weights from global) ----
    const u16* w2h = pw2 + hc * 192;
    #pragma unroll
    for (int kc = 0; kc < 6; kc++) {
      bf16x8 hf0 = *(const bf16x8*)&hid[(wm * 32 + l15) * 200 + kc * 32 + quad * 8];
      bf16x8 hf1 = *(const bf16x8*)&hid[(wm * 32 + 16 + l15) * 200 + kc * 32 + quad * 8];
      #pragma unroll
      for (int nt = 0; nt < 6; nt++) {
        bf16x8 wf = *(const bf16x8*)(w2h + nt * 18432 + kc * 32);  // nt*16*1152
        acc2[0][nt] = __builtin_amdgcn_mfma_f32_16x16x32_bf16(hf0, wf, acc2[0][nt], 0, 0, 0);
        acc2[1][nt] = __builtin_amdgcn_mfma_f32_16x16x32_bf16(hf1, wf, acc2[1][nt], 0, 0, 0);
      }
    }
    __syncthreads();   // phase B reads done before next hc's GELU overwrites
  }

  // ---- epilogue: 2 col-halves through ct overlay (last barrier already done) ----
  #pragma unroll
  for (int g = 0; g < 2; g++) {
    if (wn == g) {
      #pragma unroll
      for (int nt = 0; nt < 6; nt++) {
        int col = nt * 16 + l15;
        float bi = b2[g * 96 + col];
        #pragma unroll
        for (int mt = 0; mt < 2; mt++) {
          int row0 = wm * 32 + mt * 16 + quad * 4;
          #pragma unroll
          for (int j = 0; j < 4; j++)
            ct[(row0 + j) * 100 + col] = acc2[mt][nt][j] + bi;
        }
      }
    }
    __syncthreads();
    #pragma unroll
    for (int it = 0; it < 6; it++) {
      int cc = it * 256 + tid;
      int row = cc / 24, i = cc - row * 24;
      float4 v = *(const float4*)&ct[row * 100 + i * 4];
      long idx = (bm + row) * 192 + g * 96 + i * 4;
      const float4 rv = *(const float4*)(resid + idx);
      v.x += rv.x; v.y += rv.y; v.z += rv.z; v.w += rv.w;
      *(float4*)(out + idx) = v;
    }
    if (g == 0) __syncthreads();
  }
}

// ---------------- MFMA windowed attention: 1 wave per (window, head) ----------------
// Head-grouped blocks: all 4 waves of a block share ONE head, so the 16 KB
// bias slice is staged in LDS once per block (btab reads drop 151 -> 25 MB).
__global__ __launch_bounds__(256) void attn_kernel(
    const u16* __restrict__ qkv, const float* __restrict__ btab,
    u16* __restrict__ attn) {
  // per-wave u16: P 64x72 = 4608 | Vt 32x72 = 2304 | rsum 64 f32 = 128
  __shared__ u16 lds[4 * 7040];    // 56,320 B
  __shared__ float sbias[64 * 65]; // 16,640 B (65-stride kills quad bank alias)
  int tid = threadIdx.x;
  int wave = tid >> 6, lane = tid & 63;
  int quad = lane >> 4, l15 = lane & 15;
  int head = blockIdx.x % 6;             // same head for all 4 waves
  int grp = blockIdx.x / 6;              // 256 groups x 4 windows
  int win = grp * 4 + wave;
  int b = win >> 6, wy = (win >> 3) & 7, wx = win & 7;
  u16* lp = lds + wave * 7040;
  u16* lvt = lp + 4608;
  float* rsum = (float*)(lp + 6912);

  // stage bias slice (4096 f32) cooperatively: 4 float4 per thread
  {
    const float* bsrc = btab + head * 4096;
    #pragma unroll
    for (int i = 0; i < 4; i++) {
      int idx4 = tid + i * 256;          // float4 index, m = idx4>>4, r0 = (idx4&15)*4
      float4 v = *(const float4*)(bsrc + idx4 * 4);
      float* dst = &sbias[(idx4 >> 4) * 65 + (idx4 & 15) * 4];
      dst[0] = v.x; dst[1] = v.y; dst[2] = v.z; dst[3] = v.w;
    }
  }

  bf16x8 qb[4], ka[4];
  #pragma unroll
  for (int t = 0; t < 4; t++) {
    int n = t * 16 + l15;
    uint4 qv = {0, 0, 0, 0}, kv = {0, 0, 0, 0}, vv = {0, 0, 0, 0};
    if (n < 49) {
      int i = n / 7, j = n - i * 7;
      int y = wy * 7 + i + 3;  if (y >= 56) y -= 56;
      int xx = wx * 7 + j + 3; if (xx >= 56) xx -= 56;
      long base = ((long)(b * 3136 + y * 56 + xx)) * 576 + head * 32 + quad * 8;
      qv = *(const uint4*)(qkv + base);
      kv = *(const uint4*)(qkv + base + 192);
      vv = *(const uint4*)(qkv + base + 384);
    }
    qb[t] = *(const bf16x8*)&qv;
    ka[t] = *(const bf16x8*)&kv;
    const u16* vp = (const u16*)&vv;
    #pragma unroll
    for (int d = 0; d < 8; d++) lvt[(quad * 8 + d) * 72 + n] = vp[d];
  }

  f32x4 s[4][4];
  const f32x4 fz = {0.0f, 0.0f, 0.0f, 0.0f};
  #pragma unroll
  for (int tm = 0; tm < 4; tm++)
    #pragma unroll
    for (int tr = 0; tr < 4; tr++)
      s[tm][tr] = __builtin_amdgcn_mfma_f32_16x16x32_bf16(ka[tm], qb[tr], fz, 0, 0, 0);

  __syncthreads();   // sbias resident (uniform barrier, all waves)

  const float scale = 0.17677669529663687f;  // 32^-0.5
  float mx[4] = {-1e30f, -1e30f, -1e30f, -1e30f};
  #pragma unroll
  for (int tm = 0; tm < 4; tm++) {
    int m0 = tm * 16 + quad * 4;
    #pragma unroll
    for (int tr = 0; tr < 4; tr++) {
      int r = tr * 16 + l15;
      #pragma unroll
      for (int j = 0; j < 4; j++) {
        float v = s[tm][tr][j] * scale + sbias[(m0 + j) * 65 + r];
        s[tm][tr][j] = v;
        mx[tr] = fmaxf(mx[tr], v);
      }
    }
  }
  #pragma unroll
  for (int tr = 0; tr < 4; tr++) {
    mx[tr] = fmaxf(mx[tr], __shfl_xor(mx[tr], 16));
    mx[tr] = fmaxf(mx[tr], __shfl_xor(mx[tr], 32));
  }
  float sm[4] = {0.f, 0.f, 0.f, 0.f};
  #pragma unroll
  for (int tm = 0; tm < 4; tm++) {
    #pragma unroll
    for (int tr = 0; tr < 4; tr++) {
      int r = tr * 16 + l15;
      float e0 = __expf(s[tm][tr][0] - mx[tr]);
      float e1 = __expf(s[tm][tr][1] - mx[tr]);
      float e2 = __expf(s[tm][tr][2] - mx[tr]);
      float e3 = __expf(s[tm][tr][3] - mx[tr]);
      sm[tr] += (e0 + e1) + (e2 + e3);
      uint2 pk;
      pk.x = pk2(e0, e1);
      pk.y = pk2(e2, e3);
      *(uint2*)&lp[r * 72 + tm * 16 + quad * 4] = pk;
    }
  }
  #pragma unroll
  for (int tr = 0; tr < 4; tr++) {
    sm[tr] += __shfl_xor(sm[tr], 16);
    sm[tr] += __shfl_xor(sm[tr], 32);
  }
  if (quad == 0) {
    #pragma unroll
    for (int tr = 0; tr < 4; tr++) rsum[tr * 16 + l15] = __builtin_amdgcn_rcpf(sm[tr]);
  }

  f32x4 o[4][2] = {};
  #pragma unroll
  for (int ks = 0; ks < 2; ks++) {
    bf16x8 vb0 = *(const bf16x8*)&lvt[(l15) * 72 + ks * 32 + quad * 8];
    bf16x8 vb1 = *(const bf16x8*)&lvt[(16 + l15) * 72 + ks * 32 + quad * 8];
    #pragma unroll
    for (int rt = 0; rt < 4; rt++) {
      bf16x8 pf = *(const bf16x8*)&lp[(rt * 16 + l15) * 72 + ks * 32 + quad * 8];
      o[rt][0] = __builtin_amdgcn_mfma_f32_16x16x32_bf16(pf, vb0, o[rt][0], 0, 0, 0);
      o[rt][1] = __builtin_amdgcn_mfma_f32_16x16x32_bf16(pf, vb1, o[rt][1], 0, 0, 0);
    }
  }
  #pragma unroll
  for (int rt = 0; rt < 4; rt++) {
    #pragma unroll
    for (int j = 0; j < 4; j++) {
      int r = rt * 16 + quad * 4 + j;
      if (r < 49) {
        float inv = rsum[r];
        int i = r / 7, jj = r - i * 7;
        int y = wy * 7 + i + 3;   if (y >= 56) y -= 56;
        int xx = wx * 7 + jj + 3; if (xx >= 56) xx -= 56;
        long base = ((long)(b * 3136 + y * 56 + xx)) * 192 + head * 32 + 2 * l15;
        *(unsigned int*)&attn[base] = pk2(o[rt][0][j] * inv, o[rt][1][j] * inv);
      }
    }
  }
}

extern "C" void kernel_launch(void* const* d_in, const int* in_sizes, int n_in,
                              void* d_out, int out_size, void* d_ws, size_t ws_size,
                              hipStream_t stream) {
  (void)in_sizes; (void)n_in; (void)out_size; (void)ws_size;
  const float* x      = (const float*)d_in[0];
  const float* ln1_g  = (const float*)d_in[3];
  const float* ln1_b  = (const float*)d_in[4];
  const float* qkv_w  = (const float*)d_in[5];
  const float* qkv_b  = (const float*)d_in[6];
  const float* rpb    = (const float*)d_in[7];
  const float* proj_w = (const float*)d_in[8];
  const float* proj_b = (const float*)d_in[9];
  const float* ln2_g  = (const float*)d_in[10];
  const float* ln2_b  = (const float*)d_in[11];
  const float* fc1_w  = (const float*)d_in[12];
  const float* fc1_b  = (const float*)d_in[13];
  const float* fc2_w  = (const float*)d_in[14];
  const float* fc2_b  = (const float*)d_in[15];

  // workspace layout (bytes), M=50176:
  //   [0,            38,535,168)  x2 fp32
  //   [38,535,168,   57,802,752)  hA bf16 (ln1 out / ln2 out; btab overlays)
  //   [57,802,752,  115,605,504)  qkv bf16  (dead after proj)
  //   [115,605,504, 134,873,088)  attn bf16
  //   [173,408,256, 174,587,904)  bf16 weights
  char* ws = (char*)d_ws;
  float* x2   = (float*)(ws + 0);
  u16* hA     = (u16*)(ws + 38535168);
  float* btab = (float*)(ws + 38535168);   // live only qkv->attn
  u16* qkv    = (u16*)(ws + 57802752);
  u16* attn   = (u16*)(ws + 115605504);
  u16* wbuf   = (u16*)(ws + 173408256);
  u16* qkv_wb  = wbuf;
  u16* proj_wb = wbuf + 110592;
  u16* fc1_wb  = wbuf + 147456;
  u16* fc2_wb  = wbuf + 368640;

  cast_weights<<<dim3(864), 256, 0, stream>>>(qkv_w, proj_w, fc1_w, fc2_w,
                                              qkv_wb, proj_wb, fc1_wb, fc2_wb);
  ln_kernel<<<dim3(12544), 256, 0, stream>>>(x, ln1_g, ln1_b, hA);
  gemm_kernel<0><<<dim3(392, 3), 256, 0, stream>>>(hA, qkv_wb, qkv_b, nullptr,
                                                   qkv, 576, 192);
  build_btab<<<dim3(96), 256, 0, stream>>>(rpb, btab);
  attn_kernel<<<dim3(1536), 256, 0, stream>>>(qkv, btab, attn);
  gemm_kernel<2><<<dim3(392, 1), 256, 0, stream>>>(attn, proj_wb, proj_b, x,
                                                   x2, 192, 192);
  ln_kernel<<<dim3(12544), 256, 0, stream>>>(x2, ln2_g, ln2_b, hA);
  mlp_kernel<<<dim3(784), 256, 0, stream>>>(hA, fc1_wb, fc1_b, fc2_wb, fc2_b,
                                            x2, (float*)d_out);
}

// Round 8
// 355.300 us; speedup vs baseline: 1.2175x; 1.2175x over previous
//
#include <hip/hip_runtime.h>

typedef unsigned short u16;
typedef __bf16 bf16x8 __attribute__((ext_vector_type(8)));
typedef __bf16 bf16x2_t __attribute__((ext_vector_type(2)));
typedef float f32x4 __attribute__((ext_vector_type(4)));

#define AS1 __attribute__((address_space(1)))
#define AS3 __attribute__((address_space(3)))

__device__ __forceinline__ void gld16(const void* g, void* l) {
  // 16B per lane: global per-lane gather -> LDS (wave-uniform base + lane*16)
  __builtin_amdgcn_global_load_lds((const AS1 void*)g, (AS3 void*)l, 16, 0, 0);
}

__device__ __forceinline__ u16 f2bf(float f) {
  union { float f; unsigned int u; } v; v.f = f;
  unsigned int u = v.u;
  u += 0x7fffu + ((u >> 16) & 1u);
  return (u16)(u >> 16);
}
__device__ __forceinline__ float bf2f(u16 h) {
  union { unsigned int u; float f; } v; v.u = ((unsigned int)h) << 16; return v.f;
}
// pack 2 fp32 -> 2 bf16 in one HW instr where available
__device__ __forceinline__ unsigned int pk2(float a, float b) {
#if __has_builtin(__builtin_amdgcn_cvt_pk_bf16_f32)
  union { bf16x2_t v; unsigned int u; } c;
  c.v = __builtin_amdgcn_cvt_pk_bf16_f32(a, b);
  return c.u;
#else
  return (unsigned int)f2bf(a) | ((unsigned int)f2bf(b) << 16);
#endif
}
// fast GELU: v * sigmoid(v*(1.5957691 + 0.0713548*v^2)); raw v_rcp (1 instr)
__device__ __forceinline__ float gelu_f(float v) {
  float u = v * (1.5957691216f + 0.0713548163f * v * v);
  return v * __builtin_amdgcn_rcpf(1.0f + __expf(-u));
}

// ---------------- cast weights fp32 -> bf16 ----------------
// proj_w gets head-interleaved column permutation to match attn's packed stores:
// attn lane holds (d, d+16) pairs -> stored at cols (2d, 2d+1) within the head.
__global__ __launch_bounds__(256) void cast_weights(
    const float* __restrict__ w0, const float* __restrict__ w1,
    const float* __restrict__ w2, const float* __restrict__ w3,
    u16* __restrict__ o0, u16* __restrict__ o1,
    u16* __restrict__ o2, u16* __restrict__ o3) {
  int i = blockIdx.x * 256 + threadIdx.x;
  if (i < 110592) o0[i] = f2bf(w0[i]);   // qkv_w 576x192
  if (i < 36864) {                        // proj_w 192x192, k-permuted
    int n = i / 192, kp = i - n * 192;
    int h = kp >> 5, dp = kp & 31;
    int d = (dp & 1) ? ((dp >> 1) + 16) : (dp >> 1);
    o1[i] = f2bf(w1[n * 192 + h * 32 + d]);
  }
  if (i < 221184) o2[i] = f2bf(w2[i]);   // fc1_w 1152x192
  if (i < 221184) o3[i] = f2bf(w3[i]);   // fc2_w 192x1152
}

// ---------------- bias table [6][64(key m)][64(query r)]; key>=49 -> -1e30 ----
__global__ __launch_bounds__(256) void build_btab(
    const float* __restrict__ rpb, float* __restrict__ btab) {
  int id = blockIdx.x * 256 + threadIdx.x;   // 96*256 = 24576
  int head = id >> 12;
  int m = (id >> 6) & 63;
  int r = id & 63;
  float v;
  if (m >= 49) v = -1e30f;                   // key mask folds into bias
  else if (r >= 49) v = 0.0f;
  else {
    int mi = m / 7, mj = m - mi * 7;
    int ri = r / 7, rj = r - ri * 7;
    v = rpb[((ri - mi + 6) * 13 + (rj - mj + 6)) * 6 + head];
  }
  btab[id] = v;
}

// ---------------- layernorm (fp32 in, bf16 out), 1 wave per row of 192 ----------------
__global__ __launch_bounds__(256) void ln_kernel(
    const float* __restrict__ x, const float* __restrict__ g,
    const float* __restrict__ b, u16* __restrict__ out) {
  int row = blockIdx.x * 4 + (threadIdx.x >> 6);
  int lane = threadIdx.x & 63;
  const float* xr = x + (long)row * 192;
  float e0 = xr[lane], e1 = xr[lane + 64], e2 = xr[lane + 128];
  float s = e0 + e1 + e2;
  #pragma unroll
  for (int o = 1; o < 64; o <<= 1) s += __shfl_xor(s, o);
  float mean = s * (1.0f / 192.0f);
  float d0 = e0 - mean, d1 = e1 - mean, d2 = e2 - mean;
  float q = d0 * d0 + d1 * d1 + d2 * d2;
  #pragma unroll
  for (int o = 1; o < 64; o <<= 1) q += __shfl_xor(q, o);
  float rstd = rsqrtf(q * (1.0f / 192.0f) + 1e-5f);
  u16* orow = out + (long)row * 192;
  orow[lane]       = f2bf(d0 * rstd * g[lane]       + b[lane]);
  orow[lane + 64]  = f2bf(d1 * rstd * g[lane + 64]  + b[lane + 64]);
  orow[lane + 128] = f2bf(d2 * rstd * g[lane + 128] + b[lane + 128]);
}

// ---------------- MFMA GEMM: out[M,N] = A[M,K] @ W[N,K]^T + bias ----------------
// Block tile BMT x 192, 4 waves 2x2 (wave tile BMT/2 x 96), 16x16x32 MFMA.
// Round-4 sync structure (double-buffered chunk=32, 2 barriers/chunk) + 3
// counter-backed fixes:
//  * STATIC staging pointers (R5's VALU fix, now WITHOUT the launch_bounds-4
//    confound): init once, advance +32/chunk. VALUBusy 46% -> ~28% expected.
//  * Division-free epilogue flush: thread owns row tid>>2, seg tid&3,
//    6 strided float4s (no cc/24, indices strength-reduced).
//  * BMT=64 for proj/fc2 (N=192): grid 392 -> 784 (1.5 -> 3 blocks/CU).
//    R3's BM=64 traffic penalty was BN=96-specific; at BN=192 extra W
//    re-reads are 29 MB (negligible).
// LDS: BMT=128: 2x20KB = 40,960 B; BMT=64: 2x16KB = 32,768 B.
// MODE 0: store bf16. MODE 1: fast-GELU -> bf16. MODE 2: +resid(fp32) -> fp32.
// Requires K % 32 == 0, N % 192 == 0, M % BMT == 0.
template<int MODE, int BMT>
__global__ __launch_bounds__(256, 3) void gemm_kernel(
    const u16* __restrict__ A, const u16* __restrict__ W,
    const float* __restrict__ bias, const float* __restrict__ resid,
    void* __restrict__ out, int N, int K) {
  constexpr int AT = BMT / 16;         // A tiles per chunk (8 or 4)
  constexpr int MT = BMT / 32;         // m-tiles per wave (4 or 2)
  constexpr int TT = AT + 12;          // total tiles per chunk (20 or 16)
  constexpr int NS = TT / 4;           // staged tiles per wave (5 or 4)
  constexpr int BUF = TT * 512;        // u16 per LDS buffer
  __shared__ u16 lds[2 * BUF];
  float* ct = (float*)lds;             // epilogue overlay: 64 x 100 fp32 (25,600 B)
  const int tid = threadIdx.x;
  const int wave = tid >> 6, lane = tid & 63;
  const int wm = wave >> 1, wn = wave & 1;
  const int quad = lane >> 4, l15 = lane & 15;
  const long bm = (long)blockIdx.x * BMT;
  const int bn = blockIdx.y * 192;
  const int NC = K >> 5;

  // ---- static per-wave staging pointers (computed ONCE) ----
  const u16* sp[NS];
  int sd[NS];
  #pragma unroll
  for (int i = 0; i < NS; i++) {
    int t = wave + i * 4;
    sp[i] = (t < AT) ? (A + (bm + t * 16 + l15) * (long)K + quad * 8)
                     : (W + (long)(bn + (t - AT) * 16 + l15) * K + quad * 8);
    sd[i] = t * 512;
  }
  auto stage = [&](u16* dst) {
    #pragma unroll
    for (int i = 0; i < NS; i++) { gld16(sp[i], dst + sd[i]); sp[i] += 32; }
  };

  stage(lds);            // chunk 0 -> buf 0
  __syncthreads();

  f32x4 acc[MT][6] = {};
  for (int c = 0; c < NC; c++) {
    const int cur = c & 1;
    if (c + 1 < NC) stage(&lds[(cur ^ 1) * BUF]);
    const u16* buf = lds + cur * BUF;
    bf16x8 af[MT];
    #pragma unroll
    for (int mt = 0; mt < MT; mt++)
      af[mt] = *(const bf16x8*)&buf[(wm * MT + mt) * 512 + lane * 8];
    #pragma unroll
    for (int nt = 0; nt < 6; nt++) {
      bf16x8 bfr = *(const bf16x8*)&buf[(AT + wn * 6 + nt) * 512 + lane * 8];
      #pragma unroll
      for (int mt = 0; mt < MT; mt++)
        acc[mt][nt] = __builtin_amdgcn_mfma_f32_16x16x32_bf16(af[mt], bfr, acc[mt][nt], 0, 0, 0);
    }
    __syncthreads();   // drains chunk c+1 staging; guards buf reuse
  }

  // ---- epilogue: (BMT/64) x 2 passes of 64 rows x 96 cols ----
  const int frow = tid >> 2, seg = tid & 3;   // flush: row + 4 segments
  #pragma unroll
  for (int h = 0; h < BMT / 64; h++) {
    #pragma unroll
    for (int g = 0; g < 2; g++) {
      const bool writer = (BMT == 128) ? (wm == h && wn == g) : (wn == g);
      if (writer) {
        #pragma unroll
        for (int nt = 0; nt < 6; nt++) {
          int col = nt * 16 + l15;
          float bi = bias[bn + g * 96 + col];
          #pragma unroll
          for (int mt = 0; mt < MT; mt++) {
            int row0 = (BMT == 128 ? 0 : wm * 32) + mt * 16 + quad * 4;
            #pragma unroll
            for (int j = 0; j < 4; j++)
              ct[(row0 + j) * 100 + col] = acc[mt][nt][j] + bi;
          }
        }
      }
      __syncthreads();
      // flush: 64 rows x 24 float4; thread = (row, seg), k-strided (no division)
      const float* cp = &ct[frow * 100 + seg * 4];
      long gbase = (bm + h * 64 + frow) * (long)N + bn + g * 96 + seg * 4;
      #pragma unroll
      for (int k = 0; k < 6; k++) {
        float4 v = *(const float4*)(cp + k * 16);
        long idx = gbase + k * 16;
        if (MODE == 2) {
          const float4 rv = *(const float4*)(resid + idx);
          v.x += rv.x; v.y += rv.y; v.z += rv.z; v.w += rv.w;
          *(float4*)((float*)out + idx) = v;
        } else {
          if (MODE == 1) {
            v.x = gelu_f(v.x); v.y = gelu_f(v.y); v.z = gelu_f(v.z); v.w = gelu_f(v.w);
          }
          uint2 pk;
          pk.x = pk2(v.x, v.y);
          pk.y = pk2(v.z, v.w);
          *(uint2*)((u16*)out + idx) = pk;
        }
      }
      if (!(h == BMT / 64 - 1 && g == 1)) __syncthreads();
    }
  }
}

// ---------------- MFMA windowed attention: 1 wave per (window, head) ----------------
// Head-grouped blocks: all 4 waves of a block share ONE head, so the 16 KB
// bias slice is staged in LDS once per block (btab reads drop 151 -> 25 MB).
__global__ __launch_bounds__(256) void attn_kernel(
    const u16* __restrict__ qkv, const float* __restrict__ btab,
    u16* __restrict__ attn) {
  // per-wave u16: P 64x72 = 4608 | Vt 32x72 = 2304 | rsum 64 f32 = 128
  __shared__ u16 lds[4 * 7040];    // 56,320 B
  __shared__ float sbias[64 * 65]; // 16,640 B (65-stride kills quad bank alias)
  int tid = threadIdx.x;
  int wave = tid >> 6, lane = tid & 63;
  int quad = lane >> 4, l15 = lane & 15;
  int head = blockIdx.x % 6;             // same head for all 4 waves
  int grp = blockIdx.x / 6;              // 256 groups x 4 windows
  int win = grp * 4 + wave;
  int b = win >> 6, wy = (win >> 3) & 7, wx = win & 7;
  u16* lp = lds + wave * 7040;
  u16* lvt = lp + 4608;
  float* rsum = (float*)(lp + 6912);

  // stage bias slice (4096 f32) cooperatively: 4 float4 per thread
  {
    const float* bsrc = btab + head * 4096;
    #pragma unroll
    for (int i = 0; i < 4; i++) {
      int idx4 = tid + i * 256;          // float4 index, m = idx4>>4, r0 = (idx4&15)*4
      float4 v = *(const float4*)(bsrc + idx4 * 4);
      float* dst = &sbias[(idx4 >> 4) * 65 + (idx4 & 15) * 4];
      dst[0] = v.x; dst[1] = v.y; dst[2] = v.z; dst[3] = v.w;
    }
  }

  bf16x8 qb[4], ka[4];
  #pragma unroll
  for (int t = 0; t < 4; t++) {
    int n = t * 16 + l15;
    uint4 qv = {0, 0, 0, 0}, kv = {0, 0, 0, 0}, vv = {0, 0, 0, 0};
    if (n < 49) {
      int i = n / 7, j = n - i * 7;
      int y = wy * 7 + i + 3;  if (y >= 56) y -= 56;
      int xx = wx * 7 + j + 3; if (xx >= 56) xx -= 56;
      long base = ((long)(b * 3136 + y * 56 + xx)) * 576 + head * 32 + quad * 8;
      qv = *(const uint4*)(qkv + base);
      kv = *(const uint4*)(qkv + base + 192);
      vv = *(const uint4*)(qkv + base + 384);
    }
    qb[t] = *(const bf16x8*)&qv;
    ka[t] = *(const bf16x8*)&kv;
    const u16* vp = (const u16*)&vv;
    #pragma unroll
    for (int d = 0; d < 8; d++) lvt[(quad * 8 + d) * 72 + n] = vp[d];
  }

  f32x4 s[4][4];
  const f32x4 fz = {0.0f, 0.0f, 0.0f, 0.0f};
  #pragma unroll
  for (int tm = 0; tm < 4; tm++)
    #pragma unroll
    for (int tr = 0; tr < 4; tr++)
      s[tm][tr] = __builtin_amdgcn_mfma_f32_16x16x32_bf16(ka[tm], qb[tr], fz, 0, 0, 0);

  __syncthreads();   // sbias resident (uniform barrier, all waves)

  const float scale = 0.17677669529663687f;  // 32^-0.5
  float mx[4] = {-1e30f, -1e30f, -1e30f, -1e30f};
  #pragma unroll
  for (int tm = 0; tm < 4; tm++) {
    int m0 = tm * 16 + quad * 4;
    #pragma unroll
    for (int tr = 0; tr < 4; tr++) {
      int r = tr * 16 + l15;
      #pragma unroll
      for (int j = 0; j < 4; j++) {
        float v = s[tm][tr][j] * scale + sbias[(m0 + j) * 65 + r];
        s[tm][tr][j] = v;
        mx[tr] = fmaxf(mx[tr], v);
      }
    }
  }
  #pragma unroll
  for (int tr = 0; tr < 4; tr++) {
    mx[tr] = fmaxf(mx[tr], __shfl_xor(mx[tr], 16));
    mx[tr] = fmaxf(mx[tr], __shfl_xor(mx[tr], 32));
  }
  float sm[4] = {0.f, 0.f, 0.f, 0.f};
  #pragma unroll
  for (int tm = 0; tm < 4; tm++) {
    #pragma unroll
    for (int tr = 0; tr < 4; tr++) {
      int r = tr * 16 + l15;
      float e0 = __expf(s[tm][tr][0] - mx[tr]);
      float e1 = __expf(s[tm][tr][1] - mx[tr]);
      float e2 = __expf(s[tm][tr][2] - mx[tr]);
      float e3 = __expf(s[tm][tr][3] - mx[tr]);
      sm[tr] += (e0 + e1) + (e2 + e3);
      uint2 pk;
      pk.x = pk2(e0, e1);
      pk.y = pk2(e2, e3);
      *(uint2*)&lp[r * 72 + tm * 16 + quad * 4] = pk;
    }
  }
  #pragma unroll
  for (int tr = 0; tr < 4; tr++) {
    sm[tr] += __shfl_xor(sm[tr], 16);
    sm[tr] += __shfl_xor(sm[tr], 32);
  }
  if (quad == 0) {
    #pragma unroll
    for (int tr = 0; tr < 4; tr++) rsum[tr * 16 + l15] = __builtin_amdgcn_rcpf(sm[tr]);
  }

  f32x4 o[4][2] = {};
  #pragma unroll
  for (int ks = 0; ks < 2; ks++) {
    bf16x8 vb0 = *(const bf16x8*)&lvt[(l15) * 72 + ks * 32 + quad * 8];
    bf16x8 vb1 = *(const bf16x8*)&lvt[(16 + l15) * 72 + ks * 32 + quad * 8];
    #pragma unroll
    for (int rt = 0; rt < 4; rt++) {
      bf16x8 pf = *(const bf16x8*)&lp[(rt * 16 + l15) * 72 + ks * 32 + quad * 8];
      o[rt][0] = __builtin_amdgcn_mfma_f32_16x16x32_bf16(pf, vb0, o[rt][0], 0, 0, 0);
      o[rt][1] = __builtin_amdgcn_mfma_f32_16x16x32_bf16(pf, vb1, o[rt][1], 0, 0, 0);
    }
  }
  #pragma unroll
  for (int rt = 0; rt < 4; rt++) {
    #pragma unroll
    for (int j = 0; j < 4; j++) {
      int r = rt * 16 + quad * 4 + j;
      if (r < 49) {
        float inv = rsum[r];
        int i = r / 7, jj = r - i * 7;
        int y = wy * 7 + i + 3;   if (y >= 56) y -= 56;
        int xx = wx * 7 + jj + 3; if (xx >= 56) xx -= 56;
        long base = ((long)(b * 3136 + y * 56 + xx)) * 192 + head * 32 + 2 * l15;
        *(unsigned int*)&attn[base] = pk2(o[rt][0][j] * inv, o[rt][1][j] * inv);
      }
    }
  }
}

extern "C" void kernel_launch(void* const* d_in, const int* in_sizes, int n_in,
                              void* d_out, int out_size, void* d_ws, size_t ws_size,
                              hipStream_t stream) {
  (void)in_sizes; (void)n_in; (void)out_size; (void)ws_size;
  const float* x      = (const float*)d_in[0];
  const float* ln1_g  = (const float*)d_in[3];
  const float* ln1_b  = (const float*)d_in[4];
  const float* qkv_w  = (const float*)d_in[5];
  const float* qkv_b  = (const float*)d_in[6];
  const float* rpb    = (const float*)d_in[7];
  const float* proj_w = (const float*)d_in[8];
  const float* proj_b = (const float*)d_in[9];
  const float* ln2_g  = (const float*)d_in[10];
  const float* ln2_b  = (const float*)d_in[11];
  const float* fc1_w  = (const float*)d_in[12];
  const float* fc1_b  = (const float*)d_in[13];
  const float* fc2_w  = (const float*)d_in[14];
  const float* fc2_b  = (const float*)d_in[15];

  // workspace layout (bytes), M=50176:
  //   [0,            38,535,168)  x2 fp32
  //   [38,535,168,   57,802,752)  hA bf16 (ln1 out / ln2 out; btab overlays)
  //   [57,802,752,  115,605,504)  qkv bf16  --+ dead after proj; hid bf16
  //   [115,605,504, 134,873,088)  attn bf16 --+ overlays [57,802,752, ...)
  //   [173,408,256, 174,587,904)  bf16 weights
  char* ws = (char*)d_ws;
  float* x2   = (float*)(ws + 0);
  u16* hA     = (u16*)(ws + 38535168);
  float* btab = (float*)(ws + 38535168);   // live only qkv->attn
  u16* qkv    = (u16*)(ws + 57802752);
  u16* attn   = (u16*)(ws + 115605504);
  u16* hid    = (u16*)(ws + 57802752);
  u16* wbuf   = (u16*)(ws + 173408256);
  u16* qkv_wb  = wbuf;
  u16* proj_wb = wbuf + 110592;
  u16* fc1_wb  = wbuf + 147456;
  u16* fc2_wb  = wbuf + 368640;

  cast_weights<<<dim3(864), 256, 0, stream>>>(qkv_w, proj_w, fc1_w, fc2_w,
                                              qkv_wb, proj_wb, fc1_wb, fc2_wb);
  ln_kernel<<<dim3(12544), 256, 0, stream>>>(x, ln1_g, ln1_b, hA);
  gemm_kernel<0, 128><<<dim3(392, 3), 256, 0, stream>>>(hA, qkv_wb, qkv_b, nullptr,
                                                        qkv, 576, 192);
  build_btab<<<dim3(96), 256, 0, stream>>>(rpb, btab);
  attn_kernel<<<dim3(1536), 256, 0, stream>>>(qkv, btab, attn);
  gemm_kernel<2, 64><<<dim3(784, 1), 256, 0, stream>>>(attn, proj_wb, proj_b, x,
                                                       x2, 192, 192);
  ln_kernel<<<dim3(12544), 256, 0, stream>>>(x2, ln2_g, ln2_b, hA);
  gemm_kernel<1, 128><<<dim3(392, 6), 256, 0, stream>>>(hA, fc1_wb, fc1_b, nullptr,
                                                        hid, 1152, 192);
  gemm_kernel<2, 64><<<dim3(784, 1), 256, 0, stream>>>(hid, fc2_wb, fc2_b, x2,
                                                       (float*)d_out, 192, 1152);
}

// Round 9
// 324.299 us; speedup vs baseline: 1.3339x; 1.0956x over previous
//
#include <hip/hip_runtime.h>

typedef unsigned short u16;
typedef __bf16 bf16x8 __attribute__((ext_vector_type(8)));
typedef __bf16 bf16x2_t __attribute__((ext_vector_type(2)));
typedef float f32x4 __attribute__((ext_vector_type(4)));

#define AS1 __attribute__((address_space(1)))
#define AS3 __attribute__((address_space(3)))

__device__ __forceinline__ void gld16(const void* g, void* l) {
  // 16B per lane: global per-lane gather -> LDS (wave-uniform base + lane*16)
  __builtin_amdgcn_global_load_lds((const AS1 void*)g, (AS3 void*)l, 16, 0, 0);
}

__device__ __forceinline__ u16 f2bf(float f) {
  union { float f; unsigned int u; } v; v.f = f;
  unsigned int u = v.u;
  u += 0x7fffu + ((u >> 16) & 1u);
  return (u16)(u >> 16);
}
__device__ __forceinline__ float bf2f(u16 h) {
  union { unsigned int u; float f; } v; v.u = ((unsigned int)h) << 16; return v.f;
}
// pack 2 fp32 -> 2 bf16 in one HW instr where available
__device__ __forceinline__ unsigned int pk2(float a, float b) {
#if __has_builtin(__builtin_amdgcn_cvt_pk_bf16_f32)
  union { bf16x2_t v; unsigned int u; } c;
  c.v = __builtin_amdgcn_cvt_pk_bf16_f32(a, b);
  return c.u;
#else
  return (unsigned int)f2bf(a) | ((unsigned int)f2bf(b) << 16);
#endif
}
// fast GELU: v * sigmoid(v*(1.5957691 + 0.0713548*v^2)); raw v_rcp (1 instr)
__device__ __forceinline__ float gelu_f(float v) {
  float u = v * (1.5957691216f + 0.0713548163f * v * v);
  return v * __builtin_amdgcn_rcpf(1.0f + __expf(-u));
}

// ---------------- cast weights fp32 -> bf16 ----------------
// proj_w gets head-interleaved column permutation to match attn's packed stores:
// attn lane holds (d, d+16) pairs -> stored at cols (2d, 2d+1) within the head.
__global__ __launch_bounds__(256) void cast_weights(
    const float* __restrict__ w0, const float* __restrict__ w1,
    const float* __restrict__ w2, const float* __restrict__ w3,
    u16* __restrict__ o0, u16* __restrict__ o1,
    u16* __restrict__ o2, u16* __restrict__ o3) {
  int i = blockIdx.x * 256 + threadIdx.x;
  if (i < 110592) o0[i] = f2bf(w0[i]);   // qkv_w 576x192
  if (i < 36864) {                        // proj_w 192x192, k-permuted
    int n = i / 192, kp = i - n * 192;
    int h = kp >> 5, dp = kp & 31;
    int d = (dp & 1) ? ((dp >> 1) + 16) : (dp >> 1);
    o1[i] = f2bf(w1[n * 192 + h * 32 + d]);
  }
  if (i < 221184) o2[i] = f2bf(w2[i]);   // fc1_w 1152x192
  if (i < 221184) o3[i] = f2bf(w3[i]);   // fc2_w 192x1152
}

// ---------------- bias table [6][64(key m)][64(query r)]; key>=49 -> -1e30 ----
__global__ __launch_bounds__(256) void build_btab(
    const float* __restrict__ rpb, float* __restrict__ btab) {
  int id = blockIdx.x * 256 + threadIdx.x;   // 96*256 = 24576
  int head = id >> 12;
  int m = (id >> 6) & 63;
  int r = id & 63;
  float v;
  if (m >= 49) v = -1e30f;                   // key mask folds into bias
  else if (r >= 49) v = 0.0f;
  else {
    int mi = m / 7, mj = m - mi * 7;
    int ri = r / 7, rj = r - ri * 7;
    v = rpb[((ri - mi + 6) * 13 + (rj - mj + 6)) * 6 + head];
  }
  btab[id] = v;
}

// ---------------- layernorm (fp32 in, bf16 out), 1 wave per row of 192 ----------------
__global__ __launch_bounds__(256) void ln_kernel(
    const float* __restrict__ x, const float* __restrict__ g,
    const float* __restrict__ b, u16* __restrict__ out) {
  int row = blockIdx.x * 4 + (threadIdx.x >> 6);
  int lane = threadIdx.x & 63;
  const float* xr = x + (long)row * 192;
  float e0 = xr[lane], e1 = xr[lane + 64], e2 = xr[lane + 128];
  float s = e0 + e1 + e2;
  #pragma unroll
  for (int o = 1; o < 64; o <<= 1) s += __shfl_xor(s, o);
  float mean = s * (1.0f / 192.0f);
  float d0 = e0 - mean, d1 = e1 - mean, d2 = e2 - mean;
  float q = d0 * d0 + d1 * d1 + d2 * d2;
  #pragma unroll
  for (int o = 1; o < 64; o <<= 1) q += __shfl_xor(q, o);
  float rstd = rsqrtf(q * (1.0f / 192.0f) + 1e-5f);
  u16* orow = out + (long)row * 192;
  orow[lane]       = f2bf(d0 * rstd * g[lane]       + b[lane]);
  orow[lane + 64]  = f2bf(d1 * rstd * g[lane + 64]  + b[lane + 64]);
  orow[lane + 128] = f2bf(d2 * rstd * g[lane + 128] + b[lane + 128]);
}

// ---------------- WEIGHTS-STATIONARY GEMM (K == 192): zero main-loop barriers ----
// Evidence through R8: barrier+vmcnt(0)-drain per 32-K-chunk is the floor
// (VALU 7%, MFMA 10%, HBM 18%, all idle). This kernel removes ALL of it:
//  * W-block [96 x 192] = 36,864 B staged into LDS ONCE (fragment-ordered,
//    36 tiles). The ONLY barrier in the kernel.
//  * A-fragments for the wave's 32 rows issued to REGISTERS before the
//    barrier (independent of LDS) -> latency hidden under W-stage+barrier.
//  * 72 MFMAs vs LDS-resident W frags; direct global stores. No staging,
//    no LDS writes, no barriers -> waves fully independent, compiler free.
// Block = 128 rows x 96 cols; wave = 32 rows x 96 cols (acc 2x6 f32x4).
// Grid (392, N/96). 3 blocks/CU (LDS 110 KB < 160; VGPR ~130).
// MODE 0: bf16 out. MODE 1: gelu -> bf16. MODE 2: +resid(fp32) -> fp32.
template<int MODE>
__global__ __launch_bounds__(256, 3) void wsgemm_kernel(
    const u16* __restrict__ A, const u16* __restrict__ W,
    const float* __restrict__ bias, const float* __restrict__ resid,
    void* __restrict__ out, int N) {
  __shared__ u16 wlds[36 * 512];       // 36,864 B
  const int tid = threadIdx.x;
  const int wave = tid >> 6, lane = tid & 63;
  const int quad = lane >> 4, l15 = lane & 15;
  const int bn = blockIdx.y * 96;
  const long bm = (long)blockIdx.x * 128 + wave * 32;

  // ---- issue A-fragment loads FIRST (regs; independent of LDS staging) ----
  bf16x8 af[2][6];
  #pragma unroll
  for (int mt = 0; mt < 2; mt++)
    #pragma unroll
    for (int kc = 0; kc < 6; kc++)
      af[mt][kc] = *(const bf16x8*)&A[(bm + mt * 16 + l15) * 192 + kc * 32 + quad * 8];

  // ---- stage W-block: 36 fragment-ordered 1KB tiles, 9 gld16 per wave ----
  #pragma unroll
  for (int i = 0; i < 9; i++) {
    int t = wave + i * 4;              // t = kc*6 + nt
    int kc = t / 6, nt = t - kc * 6;
    gld16(W + (long)(bn + nt * 16 + l15) * 192 + kc * 32 + quad * 8,
          &wlds[t * 512]);
  }

  float bi[6];
  #pragma unroll
  for (int nt = 0; nt < 6; nt++) bi[nt] = bias[bn + nt * 16 + l15];

  __syncthreads();                     // W resident (A drained too — was in flight)

  // ---- 72 MFMAs, barrier-free ----
  f32x4 acc[2][6] = {};
  #pragma unroll
  for (int kc = 0; kc < 6; kc++) {
    #pragma unroll
    for (int nt = 0; nt < 6; nt++) {
      bf16x8 wf = *(const bf16x8*)&wlds[(kc * 6 + nt) * 512 + lane * 8];
      acc[0][nt] = __builtin_amdgcn_mfma_f32_16x16x32_bf16(af[0][kc], wf, acc[0][nt], 0, 0, 0);
      acc[1][nt] = __builtin_amdgcn_mfma_f32_16x16x32_bf16(af[1][kc], wf, acc[1][nt], 0, 0, 0);
    }
  }

  // ---- epilogue: direct stores; D layout row = bm+mt*16+quad*4+j, col = bn+nt*16+l15
  #pragma unroll
  for (int mt = 0; mt < 2; mt++) {
    #pragma unroll
    for (int nt = 0; nt < 6; nt++) {
      const long col = bn + nt * 16 + l15;
      #pragma unroll
      for (int j = 0; j < 4; j++) {
        const long row = bm + mt * 16 + quad * 4 + j;
        const long idx = row * (long)N + col;
        float v = acc[mt][nt][j] + bi[nt];
        if (MODE == 2) {
          ((float*)out)[idx] = v + resid[idx];
        } else {
          if (MODE == 1) v = gelu_f(v);
          ((u16*)out)[idx] = f2bf(v);
        }
      }
    }
  }
}

// ---------------- MFMA GEMM (fc2, K=1152): R4 structure + static staging ----
// Block tile 128x192, 4 waves 2x2, double-buffered chunk=32.
template<int MODE>
__global__ __launch_bounds__(256, 3) void gemm_kernel(
    const u16* __restrict__ A, const u16* __restrict__ W,
    const float* __restrict__ bias, const float* __restrict__ resid,
    void* __restrict__ out, int N, int K) {
  constexpr int TT = 20;               // 8 A-tiles + 12 B-tiles per chunk
  constexpr int BUF = TT * 512;
  __shared__ u16 lds[2 * BUF];         // 40,960 B
  float* ct = (float*)lds;             // epilogue overlay: 64 x 100 fp32
  const int tid = threadIdx.x;
  const int wave = tid >> 6, lane = tid & 63;
  const int wm = wave >> 1, wn = wave & 1;
  const int quad = lane >> 4, l15 = lane & 15;
  const long bm = (long)blockIdx.x * 128;
  const int bn = blockIdx.y * 192;
  const int NC = K >> 5;

  // static per-wave staging pointers (computed once, advanced +32/chunk)
  const u16* sp[5];
  int sd[5];
  #pragma unroll
  for (int i = 0; i < 5; i++) {
    int t = wave + i * 4;
    sp[i] = (t < 8) ? (A + (bm + t * 16 + l15) * (long)K + quad * 8)
                    : (W + (long)(bn + (t - 8) * 16 + l15) * K + quad * 8);
    sd[i] = t * 512;
  }
  auto stage = [&](u16* dst) {
    #pragma unroll
    for (int i = 0; i < 5; i++) { gld16(sp[i], dst + sd[i]); sp[i] += 32; }
  };

  stage(lds);
  __syncthreads();

  f32x4 acc[4][6] = {};
  for (int c = 0; c < NC; c++) {
    const int cur = c & 1;
    if (c + 1 < NC) stage(&lds[(cur ^ 1) * BUF]);
    const u16* buf = lds + cur * BUF;
    bf16x8 af[4];
    #pragma unroll
    for (int mt = 0; mt < 4; mt++)
      af[mt] = *(const bf16x8*)&buf[(wm * 4 + mt) * 512 + lane * 8];
    #pragma unroll
    for (int nt = 0; nt < 6; nt++) {
      bf16x8 bfr = *(const bf16x8*)&buf[(8 + wn * 6 + nt) * 512 + lane * 8];
      #pragma unroll
      for (int mt = 0; mt < 4; mt++)
        acc[mt][nt] = __builtin_amdgcn_mfma_f32_16x16x32_bf16(af[mt], bfr, acc[mt][nt], 0, 0, 0);
    }
    __syncthreads();
  }

  // epilogue: 4 passes (2 row-halves h x 2 col-halves g), division-free flush
  const int frow = tid >> 2, seg = tid & 3;
  #pragma unroll
  for (int h = 0; h < 2; h++) {
    #pragma unroll
    for (int g = 0; g < 2; g++) {
      if (wm == h && wn == g) {
        #pragma unroll
        for (int nt = 0; nt < 6; nt++) {
          int col = nt * 16 + l15;
          float bi = bias[bn + g * 96 + col];
          #pragma unroll
          for (int mt = 0; mt < 4; mt++) {
            int row0 = mt * 16 + quad * 4;
            #pragma unroll
            for (int j = 0; j < 4; j++)
              ct[(row0 + j) * 100 + col] = acc[mt][nt][j] + bi;
          }
        }
      }
      __syncthreads();
      const float* cp = &ct[frow * 100 + seg * 4];
      long gbase = (bm + h * 64 + frow) * (long)N + bn + g * 96 + seg * 4;
      #pragma unroll
      for (int k = 0; k < 6; k++) {
        float4 v = *(const float4*)(cp + k * 16);
        long idx = gbase + k * 16;
        if (MODE == 2) {
          const float4 rv = *(const float4*)(resid + idx);
          v.x += rv.x; v.y += rv.y; v.z += rv.z; v.w += rv.w;
          *(float4*)((float*)out + idx) = v;
        } else {
          if (MODE == 1) {
            v.x = gelu_f(v.x); v.y = gelu_f(v.y); v.z = gelu_f(v.z); v.w = gelu_f(v.w);
          }
          uint2 pk;
          pk.x = pk2(v.x, v.y);
          pk.y = pk2(v.z, v.w);
          *(uint2*)((u16*)out + idx) = pk;
        }
      }
      if (!(h == 1 && g == 1)) __syncthreads();
    }
  }
}

// ---------------- MFMA windowed attention: 1 wave per (window, head) ----------------
// Head-grouped blocks: all 4 waves of a block share ONE head, so the 16 KB
// bias slice is staged in LDS once per block (btab reads drop 151 -> 25 MB).
__global__ __launch_bounds__(256) void attn_kernel(
    const u16* __restrict__ qkv, const float* __restrict__ btab,
    u16* __restrict__ attn) {
  // per-wave u16: P 64x72 = 4608 | Vt 32x72 = 2304 | rsum 64 f32 = 128
  __shared__ u16 lds[4 * 7040];    // 56,320 B
  __shared__ float sbias[64 * 65]; // 16,640 B (65-stride kills quad bank alias)
  int tid = threadIdx.x;
  int wave = tid >> 6, lane = tid & 63;
  int quad = lane >> 4, l15 = lane & 15;
  int head = blockIdx.x % 6;             // same head for all 4 waves
  int grp = blockIdx.x / 6;              // 256 groups x 4 windows
  int win = grp * 4 + wave;
  int b = win >> 6, wy = (win >> 3) & 7, wx = win & 7;
  u16* lp = lds + wave * 7040;
  u16* lvt = lp + 4608;
  float* rsum = (float*)(lp + 6912);

  // stage bias slice (4096 f32) cooperatively: 4 float4 per thread
  {
    const float* bsrc = btab + head * 4096;
    #pragma unroll
    for (int i = 0; i < 4; i++) {
      int idx4 = tid + i * 256;          // float4 index, m = idx4>>4, r0 = (idx4&15)*4
      float4 v = *(const float4*)(bsrc + idx4 * 4);
      float* dst = &sbias[(idx4 >> 4) * 65 + (idx4 & 15) * 4];
      dst[0] = v.x; dst[1] = v.y; dst[2] = v.z; dst[3] = v.w;
    }
  }

  bf16x8 qb[4], ka[4];
  #pragma unroll
  for (int t = 0; t < 4; t++) {
    int n = t * 16 + l15;
    uint4 qv = {0, 0, 0, 0}, kv = {0, 0, 0, 0}, vv = {0, 0, 0, 0};
    if (n < 49) {
      int i = n / 7, j = n - i * 7;
      int y = wy * 7 + i + 3;  if (y >= 56) y -= 56;
      int xx = wx * 7 + j + 3; if (xx >= 56) xx -= 56;
      long base = ((long)(b * 3136 + y * 56 + xx)) * 576 + head * 32 + quad * 8;
      qv = *(const uint4*)(qkv + base);
      kv = *(const uint4*)(qkv + base + 192);
      vv = *(const uint4*)(qkv + base + 384);
    }
    qb[t] = *(const bf16x8*)&qv;
    ka[t] = *(const bf16x8*)&kv;
    const u16* vp = (const u16*)&vv;
    #pragma unroll
    for (int d = 0; d < 8; d++) lvt[(quad * 8 + d) * 72 + n] = vp[d];
  }

  f32x4 s[4][4];
  const f32x4 fz = {0.0f, 0.0f, 0.0f, 0.0f};
  #pragma unroll
  for (int tm = 0; tm < 4; tm++)
    #pragma unroll
    for (int tr = 0; tr < 4; tr++)
      s[tm][tr] = __builtin_amdgcn_mfma_f32_16x16x32_bf16(ka[tm], qb[tr], fz, 0, 0, 0);

  __syncthreads();   // sbias resident (uniform barrier, all waves)

  const float scale = 0.17677669529663687f;  // 32^-0.5
  float mx[4] = {-1e30f, -1e30f, -1e30f, -1e30f};
  #pragma unroll
  for (int tm = 0; tm < 4; tm++) {
    int m0 = tm * 16 + quad * 4;
    #pragma unroll
    for (int tr = 0; tr < 4; tr++) {
      int r = tr * 16 + l15;
      #pragma unroll
      for (int j = 0; j < 4; j++) {
        float v = s[tm][tr][j] * scale + sbias[(m0 + j) * 65 + r];
        s[tm][tr][j] = v;
        mx[tr] = fmaxf(mx[tr], v);
      }
    }
  }
  #pragma unroll
  for (int tr = 0; tr < 4; tr++) {
    mx[tr] = fmaxf(mx[tr], __shfl_xor(mx[tr], 16));
    mx[tr] = fmaxf(mx[tr], __shfl_xor(mx[tr], 32));
  }
  float sm[4] = {0.f, 0.f, 0.f, 0.f};
  #pragma unroll
  for (int tm = 0; tm < 4; tm++) {
    #pragma unroll
    for (int tr = 0; tr < 4; tr++) {
      int r = tr * 16 + l15;
      float e0 = __expf(s[tm][tr][0] - mx[tr]);
      float e1 = __expf(s[tm][tr][1] - mx[tr]);
      float e2 = __expf(s[tm][tr][2] - mx[tr]);
      float e3 = __expf(s[tm][tr][3] - mx[tr]);
      sm[tr] += (e0 + e1) + (e2 + e3);
      uint2 pk;
      pk.x = pk2(e0, e1);
      pk.y = pk2(e2, e3);
      *(uint2*)&lp[r * 72 + tm * 16 + quad * 4] = pk;
    }
  }
  #pragma unroll
  for (int tr = 0; tr < 4; tr++) {
    sm[tr] += __shfl_xor(sm[tr], 16);
    sm[tr] += __shfl_xor(sm[tr], 32);
  }
  if (quad == 0) {
    #pragma unroll
    for (int tr = 0; tr < 4; tr++) rsum[tr * 16 + l15] = __builtin_amdgcn_rcpf(sm[tr]);
  }

  f32x4 o[4][2] = {};
  #pragma unroll
  for (int ks = 0; ks < 2; ks++) {
    bf16x8 vb0 = *(const bf16x8*)&lvt[(l15) * 72 + ks * 32 + quad * 8];
    bf16x8 vb1 = *(const bf16x8*)&lvt[(16 + l15) * 72 + ks * 32 + quad * 8];
    #pragma unroll
    for (int rt = 0; rt < 4; rt++) {
      bf16x8 pf = *(const bf16x8*)&lp[(rt * 16 + l15) * 72 + ks * 32 + quad * 8];
      o[rt][0] = __builtin_amdgcn_mfma_f32_16x16x32_bf16(pf, vb0, o[rt][0], 0, 0, 0);
      o[rt][1] = __builtin_amdgcn_mfma_f32_16x16x32_bf16(pf, vb1, o[rt][1], 0, 0, 0);
    }
  }
  #pragma unroll
  for (int rt = 0; rt < 4; rt++) {
    #pragma unroll
    for (int j = 0; j < 4; j++) {
      int r = rt * 16 + quad * 4 + j;
      if (r < 49) {
        float inv = rsum[r];
        int i = r / 7, jj = r - i * 7;
        int y = wy * 7 + i + 3;   if (y >= 56) y -= 56;
        int xx = wx * 7 + jj + 3; if (xx >= 56) xx -= 56;
        long base = ((long)(b * 3136 + y * 56 + xx)) * 192 + head * 32 + 2 * l15;
        *(unsigned int*)&attn[base] = pk2(o[rt][0][j] * inv, o[rt][1][j] * inv);
      }
    }
  }
}

extern "C" void kernel_launch(void* const* d_in, const int* in_sizes, int n_in,
                              void* d_out, int out_size, void* d_ws, size_t ws_size,
                              hipStream_t stream) {
  (void)in_sizes; (void)n_in; (void)out_size; (void)ws_size;
  const float* x      = (const float*)d_in[0];
  const float* ln1_g  = (const float*)d_in[3];
  const float* ln1_b  = (const float*)d_in[4];
  const float* qkv_w  = (const float*)d_in[5];
  const float* qkv_b  = (const float*)d_in[6];
  const float* rpb    = (const float*)d_in[7];
  const float* proj_w = (const float*)d_in[8];
  const float* proj_b = (const float*)d_in[9];
  const float* ln2_g  = (const float*)d_in[10];
  const float* ln2_b  = (const float*)d_in[11];
  const float* fc1_w  = (const float*)d_in[12];
  const float* fc1_b  = (const float*)d_in[13];
  const float* fc2_w  = (const float*)d_in[14];
  const float* fc2_b  = (const float*)d_in[15];

  // workspace layout (bytes), M=50176:
  //   [0,            38,535,168)  x2 fp32
  //   [38,535,168,   57,802,752)  hA bf16 (ln1 out / ln2 out; btab overlays)
  //   [57,802,752,  115,605,504)  qkv bf16  --+ dead after proj; hid bf16
  //   [115,605,504, 134,873,088)  attn bf16 --+ overlays [57,802,752, ...)
  //   [173,408,256, 174,587,904)  bf16 weights
  char* ws = (char*)d_ws;
  float* x2   = (float*)(ws + 0);
  u16* hA     = (u16*)(ws + 38535168);
  float* btab = (float*)(ws + 38535168);   // live only qkv->attn
  u16* qkv    = (u16*)(ws + 57802752);
  u16* attn   = (u16*)(ws + 115605504);
  u16* hid    = (u16*)(ws + 57802752);
  u16* wbuf   = (u16*)(ws + 173408256);
  u16* qkv_wb  = wbuf;
  u16* proj_wb = wbuf + 110592;
  u16* fc1_wb  = wbuf + 147456;
  u16* fc2_wb  = wbuf + 368640;

  cast_weights<<<dim3(864), 256, 0, stream>>>(qkv_w, proj_w, fc1_w, fc2_w,
                                              qkv_wb, proj_wb, fc1_wb, fc2_wb);
  ln_kernel<<<dim3(12544), 256, 0, stream>>>(x, ln1_g, ln1_b, hA);
  wsgemm_kernel<0><<<dim3(392, 6), 256, 0, stream>>>(hA, qkv_wb, qkv_b, nullptr,
                                                     qkv, 576);
  build_btab<<<dim3(96), 256, 0, stream>>>(rpb, btab);
  attn_kernel<<<dim3(1536), 256, 0, stream>>>(qkv, btab, attn);
  wsgemm_kernel<2><<<dim3(392, 2), 256, 0, stream>>>(attn, proj_wb, proj_b, x,
                                                     x2, 192);
  ln_kernel<<<dim3(12544), 256, 0, stream>>>(x2, ln2_g, ln2_b, hA);
  wsgemm_kernel<1><<<dim3(392, 12), 256, 0, stream>>>(hA, fc1_wb, fc1_b, nullptr,
                                                      hid, 1152);
  gemm_kernel<2><<<dim3(392, 1), 256, 0, stream>>>(hid, fc2_wb, fc2_b, x2,
                                                   (float*)d_out, 192, 1152);
}